// Round 2
// baseline (202.944 us; speedup 1.0000x reference)
//
#include <hip/hip_runtime.h>
#include <math.h>

#define NB 4096
#define NC 3
#define ND 512
#define NBC (NB + NC)                 // 4099
#define ADJ ((size_t)NBC * (size_t)NBC)

static constexpr float HID = 0.5f / 1.5f;   // 0.5 / DELTA

// ---- ws layout (float offsets) ---------------------------------------------
#define OFF_CNT  0                         // int counts[9] (pad 16)
#define OFF_CSUM 16                        // atomic center sums [3][3][ND]
#define OFF_CENT (OFF_CSUM + 9*ND)         // finalized centers [3][3][ND]
#define OFF_C2   (OFF_CENT + 9*ND)         // ||center||^2 [9] (pad 16)
#define OFF_AVG  (OFF_C2 + 16)             // avg centers [3][ND]
#define OFF_ST   (OFF_AVG + 3*ND)          // SoA stats [33][NB]
// per-modality field base f = m*11 + k, address OFF_ST + f*NB + i
//   k=0: a = 0.5 - (0.5/D)*sum p log p
//   k=1..3: p0 p1 p2
//   k=4..6: (0.5/D)*log p
//   k=7..9: F0 F1 F2   (filled by kD)
//   k=10:   pred (0.0/1.0/2.0)

__device__ __forceinline__ float dot8(const float4& a, const float4& b,
                                      const float4& c, const float4& d) {
    return a.x*c.x + a.y*c.y + a.z*c.z + a.w*c.w +
           b.x*d.x + b.y*d.y + b.z*d.z + b.w*d.w;
}

__device__ __forceinline__ float wred(float v) {
    #pragma unroll
    for (int off = 32; off > 0; off >>= 1) v += __shfl_xor(v, off, 64);
    return v;
}

// ---- kAB: label stats (SoA) + preds in LDS + class sums via atomics --------
__global__ void __launch_bounds__(256) kAB(const float* __restrict__ tf,
                                           const float* __restrict__ af,
                                           const float* __restrict__ vf,
                                           const float* __restrict__ tl,
                                           const float* __restrict__ al,
                                           const float* __restrict__ vl,
                                           float* __restrict__ ws) {
    __shared__ int spred[64][4];
    __shared__ int scnt[9];
    int t = threadIdx.x;
    if (t < 9) scnt[t] = 0;
    int r0 = blockIdx.x * 64;
    int r = t >> 2, m = t & 3;
    __syncthreads();
    if (m < 3) {
        const float* labs[3] = {tl, al, vl};
        int i = r0 + r;
        float p0 = labs[m][i*3+0], p1 = labs[m][i*3+1], p2 = labs[m][i*3+2];
        float l0 = logf(p0), l1 = logf(p1), l2 = logf(p2);
        float a = 0.5f - HID * (p0*l0 + p1*l1 + p2*l2);
        int pred = 0; float pm = p0;
        if (p1 > pm) { pred = 1; pm = p1; }
        if (p2 > pm) { pred = 2; }
        float* st = ws + OFF_ST + (size_t)(m*11)*NB + i;
        st[0*NB] = a;
        st[1*NB] = p0;  st[2*NB] = p1;  st[3*NB] = p2;
        st[4*NB] = HID*l0; st[5*NB] = HID*l1; st[6*NB] = HID*l2;
        st[10*NB] = (float)pred;
        spred[r][m] = pred;
        atomicAdd(&scnt[m*3 + pred], 1);
    }
    __syncthreads();
    if (t < 9) atomicAdd((int*)ws + OFF_CNT + t, scnt[t]);

    // phase 2: per-class column sums over this block's 64 rows
    const float* feats[3] = {tf, af, vf};
    float acc[3][3][2] = {};
    for (int rr = 0; rr < 64; ++rr) {
        int i = r0 + rr;
        #pragma unroll
        for (int mm = 0; mm < 3; ++mm) {
            float z0 = feats[mm][(size_t)i*ND + t];
            float z1 = feats[mm][(size_t)i*ND + t + 256];
            int pr = spred[rr][mm];
            #pragma unroll
            for (int c = 0; c < 3; ++c) {
                acc[mm][c][0] += (pr == c) ? z0 : 0.0f;
                acc[mm][c][1] += (pr == c) ? z1 : 0.0f;
            }
        }
    }
    #pragma unroll
    for (int mm = 0; mm < 3; ++mm)
        #pragma unroll
        for (int c = 0; c < 3; ++c) {
            atomicAdd(&ws[OFF_CSUM + (mm*3+c)*ND + t],       acc[mm][c][0]);
            atomicAdd(&ws[OFF_CSUM + (mm*3+c)*ND + t + 256], acc[mm][c][1]);
        }
}

// ---- kC: finalize centers, ||c||^2, avg centers, node-feat tail, eye -------
__global__ void __launch_bounds__(512) kC(float* __restrict__ ws, float* __restrict__ out) {
    int c = blockIdx.x, d = threadIdx.x;
    const int* cnt = (const int*)ws + OFF_CNT;
    float sq[3], avg = 0.0f;
    #pragma unroll
    for (int m = 0; m < 3; ++m) {
        float inv = 1.0f / fmaxf((float)cnt[m*3+c], 1.0f);
        float v = ws[OFF_CSUM + (m*3+c)*ND + d] * inv;
        ws[OFF_CENT + (m*3+c)*ND + d] = v;
        sq[m] = v * v;
        avg += v;
    }
    avg *= (1.0f/3.0f);
    ws[OFF_AVG + c*ND + d] = avg;
    out[ADJ + (size_t)(NB + c)*ND + d] = avg;

    __shared__ float red[3][512];
    red[0][d] = sq[0]; red[1][d] = sq[1]; red[2][d] = sq[2];
    __syncthreads();
    for (int s = 256; s > 0; s >>= 1) {
        if (d < s) {
            red[0][d] += red[0][d+s];
            red[1][d] += red[1][d+s];
            red[2][d] += red[2][d+s];
        }
        __syncthreads();
    }
    if (d < 3) ws[OFF_C2 + d*3 + c] = red[d][0];
    if (c == 0 && d < 9) {
        int rr = d / 3, cc = d % 3;
        out[(size_t)(NB + rr)*NBC + NB + cc] = (rr == cc) ? 1.0f : 0.0f;
    }
}

// ---- kD: wave-per-sample F factors + fused border --------------------------
__global__ void __launch_bounds__(256) kD(const float* __restrict__ tf,
                                          const float* __restrict__ af,
                                          const float* __restrict__ vf,
                                          const float* __restrict__ fused,
                                          const float* __restrict__ ccp,
                                          float* __restrict__ ws,
                                          float* __restrict__ out) {
    int wid = threadIdx.x >> 6, lane = threadIdx.x & 63;
    int i = blockIdx.x * 4 + wid;
    const float* feats[3] = {tf, af, vf};
    int d0 = lane * 8;

    #pragma unroll
    for (int m = 0; m < 3; ++m) {
        const float4* z4 = (const float4*)(feats[m] + ((size_t)i << 9) + d0);
        float4 za = z4[0], zb = z4[1];
        float v0 = dot8(za, zb, za, zb);
        const float4* c40 = (const float4*)(ws + OFF_CENT + (size_t)(m*3+0)*ND + d0);
        float v1 = dot8(za, zb, c40[0], c40[1]);
        const float4* c41 = (const float4*)(ws + OFF_CENT + (size_t)(m*3+1)*ND + d0);
        float v2 = dot8(za, zb, c41[0], c41[1]);
        const float4* c42 = (const float4*)(ws + OFF_CENT + (size_t)(m*3+2)*ND + d0);
        float v3 = dot8(za, zb, c42[0], c42[1]);
        v0 = wred(v0); v1 = wred(v1); v2 = wred(v2); v3 = wred(v3);
        if (lane == 0) {
            float* st = ws + OFF_ST + (size_t)(m*11)*NB + i;
            st[7*NB] = expf(v1 - 0.5f*(v0 + ws[OFF_C2 + m*3 + 0]));
            st[8*NB] = expf(v2 - 0.5f*(v0 + ws[OFF_C2 + m*3 + 1]));
            st[9*NB] = expf(v3 - 0.5f*(v0 + ws[OFF_C2 + m*3 + 2]));
        }
    }

    const float4* f4 = (const float4*)(fused + ((size_t)i << 9) + d0);
    float4 fa = f4[0], fb = f4[1];
    const float4* p0 = (const float4*)(ccp + 0*ND + d0);
    const float4* p1 = (const float4*)(ccp + 1*ND + d0);
    const float4* p2 = (const float4*)(ccp + 2*ND + d0);
    float l0 = wred(dot8(fa, fb, p0[0], p0[1]));
    float l1 = wred(dot8(fa, fb, p1[0], p1[1]));
    float l2 = wred(dot8(fa, fb, p2[0], p2[1]));
    int pf = 0; float lm = l0;
    if (l1 > lm) { pf = 1; lm = l1; }
    if (l2 > lm) { pf = 2; }
    const float4* av = (const float4*)(ws + OFF_AVG + (size_t)pf*ND + d0);
    float4 aa = av[0], ab = av[1];
    float dxx = fa.x-aa.x, dxy = fa.y-aa.y, dxz = fa.z-aa.z, dxw = fa.w-aa.w;
    float dyx = fb.x-ab.x, dyy = fb.y-ab.y, dyz = fb.z-ab.z, dyw = fb.w-ab.w;
    float dsq = wred(dxx*dxx + dxy*dxy + dxz*dxz + dxw*dxw +
                     dyx*dyx + dyy*dyy + dyz*dyz + dyw*dyw);
    if (lane == 0) {
        float wc = expf(-0.5f * dsq);
        #pragma unroll
        for (int c = 0; c < 3; ++c) {
            float v = (c == pf) ? wc : 0.0f;
            out[(size_t)i*NBC + NB + c]   = v;
            out[(size_t)(NB + c)*NBC + i] = v;
        }
    }
}

// ---- kE: B x B adjacency block (SoA coalesced j-loads, scalar i-loads) -----
__global__ void __launch_bounds__(256) kE(const float* __restrict__ ws,
                                          float* __restrict__ out) {
    int j = blockIdx.x * 256 + threadIdx.x;
    int i0 = blockIdx.y * 64;
    const float* st = ws + OFF_ST;

    float ja[3], jp[3][3], jl[3][3], jF[3][3], jpr[3];
    #pragma unroll
    for (int m = 0; m < 3; ++m) {
        const float* base = st + (size_t)(m*11)*NB + j;
        ja[m]    = base[0*NB];
        jp[m][0] = base[1*NB]; jp[m][1] = base[2*NB]; jp[m][2] = base[3*NB];
        jl[m][0] = base[4*NB]; jl[m][1] = base[5*NB]; jl[m][2] = base[6*NB];
        jF[m][0] = base[7*NB]; jF[m][1] = base[8*NB]; jF[m][2] = base[9*NB];
        jpr[m]   = base[10*NB];
    }

    for (int r = 0; r < 64; ++r) {
        int i = i0 + r;
        float sum = 0.0f;
        #pragma unroll
        for (int m = 0; m < 3; ++m) {
            const float* b = st + (size_t)(m*11)*NB + i;   // uniform -> s_loads
            float t = ja[m] + b[0*NB];
            t += b[1*NB]*jl[m][0] + b[2*NB]*jl[m][1] + b[3*NB]*jl[m][2];
            t += jp[m][0]*b[4*NB] + jp[m][1]*b[5*NB] + jp[m][2]*b[6*NB];
            t = fmaxf(t, 0.0f);
            float pi = b[10*NB];
            float Fj = (pi == 0.0f) ? jF[m][0] : ((pi == 1.0f) ? jF[m][1] : jF[m][2]);
            float pj = jpr[m];
            float Fi = (pj == 0.0f) ? b[7*NB] : ((pj == 1.0f) ? b[8*NB] : b[9*NB]);
            sum += t * (Fi * Fj);
        }
        float v = (i == j) ? 0.0f : sum * (1.0f/3.0f);
        __builtin_nontemporal_store(v, &out[(size_t)i*NBC + j]);
    }
}

extern "C" void kernel_launch(void* const* d_in, const int* in_sizes, int n_in,
                              void* d_out, int out_size, void* d_ws, size_t ws_size,
                              hipStream_t stream) {
    const float* tf    = (const float*)d_in[0];
    const float* af    = (const float*)d_in[1];
    const float* vf    = (const float*)d_in[2];
    const float* tl    = (const float*)d_in[3];
    const float* al    = (const float*)d_in[4];
    const float* vl    = (const float*)d_in[5];
    const float* fused = (const float*)d_in[6];
    const float* ccp   = (const float*)d_in[7];
    float* out = (float*)d_out;
    float* ws  = (float*)d_ws;

    // node_features rows 0..NB-1 (independent of everything else — issue first)
    hipMemcpyAsync(out + ADJ, fused, (size_t)NB * ND * sizeof(float),
                   hipMemcpyDeviceToDevice, stream);

    // zero counts + center sums (atomic accumulators)
    hipMemsetAsync(ws, 0, (OFF_CSUM + 9*ND) * sizeof(float), stream);

    kAB<<<NB/64, 256, 0, stream>>>(tf, af, vf, tl, al, vl, ws);
    kC<<<NC, 512, 0, stream>>>(ws, out);
    kD<<<NB/4, 256, 0, stream>>>(tf, af, vf, fused, ccp, ws, out);
    kE<<<dim3(NB/256, NB/64), 256, 0, stream>>>(ws, out);
}

// Round 3
// 185.017 us; speedup vs baseline: 1.0969x; 1.0969x over previous
//
#include <hip/hip_runtime.h>
#include <math.h>

#define NB 4096
#define NC 3
#define ND 512
#define NBC (NB + NC)                 // 4099
#define ADJ ((size_t)NBC * (size_t)NBC)

static constexpr float HID = 0.5f / 1.5f;   // 0.5 / DELTA

// ---- ws layout (float offsets) ---------------------------------------------
#define OFF_CNT  0                         // int counts[9] (pad 16)
#define OFF_CSUM 16                        // atomic center sums [3][3][ND]
#define OFF_CENT (OFF_CSUM + 9*ND)         // finalized centers [3][3][ND]
#define OFF_C2   (OFF_CENT + 9*ND)         // ||center||^2 [9] (pad 16)
#define OFF_AVG  (OFF_C2 + 16)             // avg centers [3][ND]
#define OFF_ST   (OFF_AVG + 3*ND)          // SoA stats [33][NB]
// field f = m*11 + k, address OFF_ST + f*NB + i
//   k=0: a = 0.5 - HID*sum p log p
//   k=1..3: p ; k=4..6: HID*log p ; k=7..9: F ; k=10: pred

__device__ __forceinline__ float dot8(const float4& a, const float4& b,
                                      const float4& c, const float4& d) {
    return a.x*c.x + a.y*c.y + a.z*c.z + a.w*c.w +
           b.x*d.x + b.y*d.y + b.z*d.z + b.w*d.w;
}

__device__ __forceinline__ float wred(float v) {
    #pragma unroll
    for (int off = 32; off > 0; off >>= 1) v += __shfl_xor(v, off, 64);
    return v;
}

// ---- kAB: label stats (SoA) + preds in LDS + class sums via atomics --------
__global__ void __launch_bounds__(256) kAB(const float* __restrict__ tf,
                                           const float* __restrict__ af,
                                           const float* __restrict__ vf,
                                           const float* __restrict__ tl,
                                           const float* __restrict__ al,
                                           const float* __restrict__ vl,
                                           float* __restrict__ ws) {
    __shared__ int spred[64][4];
    __shared__ int scnt[9];
    int t = threadIdx.x;
    if (t < 9) scnt[t] = 0;
    int r0 = blockIdx.x * 64;
    int r = t >> 2, m = t & 3;
    __syncthreads();
    if (m < 3) {
        const float* labs[3] = {tl, al, vl};
        int i = r0 + r;
        float p0 = labs[m][i*3+0], p1 = labs[m][i*3+1], p2 = labs[m][i*3+2];
        float l0 = logf(p0), l1 = logf(p1), l2 = logf(p2);
        float a = 0.5f - HID * (p0*l0 + p1*l1 + p2*l2);
        int pred = 0; float pm = p0;
        if (p1 > pm) { pred = 1; pm = p1; }
        if (p2 > pm) { pred = 2; }
        float* st = ws + OFF_ST + (size_t)(m*11)*NB + i;
        st[0*NB] = a;
        st[1*NB] = p0;  st[2*NB] = p1;  st[3*NB] = p2;
        st[4*NB] = HID*l0; st[5*NB] = HID*l1; st[6*NB] = HID*l2;
        st[10*NB] = (float)pred;
        spred[r][m] = pred;
        atomicAdd(&scnt[m*3 + pred], 1);
    }
    __syncthreads();
    if (t < 9) atomicAdd((int*)ws + OFF_CNT + t, scnt[t]);

    const float* feats[3] = {tf, af, vf};
    float acc[3][3][2] = {};
    for (int rr = 0; rr < 64; ++rr) {
        int i = r0 + rr;
        #pragma unroll
        for (int mm = 0; mm < 3; ++mm) {
            float z0 = feats[mm][(size_t)i*ND + t];
            float z1 = feats[mm][(size_t)i*ND + t + 256];
            int pr = spred[rr][mm];
            #pragma unroll
            for (int c = 0; c < 3; ++c) {
                acc[mm][c][0] += (pr == c) ? z0 : 0.0f;
                acc[mm][c][1] += (pr == c) ? z1 : 0.0f;
            }
        }
    }
    #pragma unroll
    for (int mm = 0; mm < 3; ++mm)
        #pragma unroll
        for (int c = 0; c < 3; ++c) {
            atomicAdd(&ws[OFF_CSUM + (mm*3+c)*ND + t],       acc[mm][c][0]);
            atomicAdd(&ws[OFF_CSUM + (mm*3+c)*ND + t + 256], acc[mm][c][1]);
        }
}

// ---- kC: finalize centers, ||c||^2, avg centers, node-feat tail, eye -------
__global__ void __launch_bounds__(512) kC(float* __restrict__ ws, float* __restrict__ out) {
    int c = blockIdx.x, d = threadIdx.x;
    const int* cnt = (const int*)ws + OFF_CNT;
    float sq[3], avg = 0.0f;
    #pragma unroll
    for (int m = 0; m < 3; ++m) {
        float inv = 1.0f / fmaxf((float)cnt[m*3+c], 1.0f);
        float v = ws[OFF_CSUM + (m*3+c)*ND + d] * inv;
        ws[OFF_CENT + (m*3+c)*ND + d] = v;
        sq[m] = v * v;
        avg += v;
    }
    avg *= (1.0f/3.0f);
    ws[OFF_AVG + c*ND + d] = avg;
    out[ADJ + (size_t)(NB + c)*ND + d] = avg;

    __shared__ float red[3][512];
    red[0][d] = sq[0]; red[1][d] = sq[1]; red[2][d] = sq[2];
    __syncthreads();
    for (int s = 256; s > 0; s >>= 1) {
        if (d < s) {
            red[0][d] += red[0][d+s];
            red[1][d] += red[1][d+s];
            red[2][d] += red[2][d+s];
        }
        __syncthreads();
    }
    if (d < 3) ws[OFF_C2 + d*3 + c] = red[d][0];
    if (c == 0 && d < 9) {
        int rr = d / 3, cc = d % 3;
        out[(size_t)(NB + rr)*NBC + NB + cc] = (rr == cc) ? 1.0f : 0.0f;
    }
}

// ---- kD: wave-per-sample F factors + fused border --------------------------
__global__ void __launch_bounds__(256) kD(const float* __restrict__ tf,
                                          const float* __restrict__ af,
                                          const float* __restrict__ vf,
                                          const float* __restrict__ fused,
                                          const float* __restrict__ ccp,
                                          float* __restrict__ ws,
                                          float* __restrict__ out) {
    int wid = threadIdx.x >> 6, lane = threadIdx.x & 63;
    int i = blockIdx.x * 4 + wid;
    const float* feats[3] = {tf, af, vf};
    int d0 = lane * 8;

    #pragma unroll
    for (int m = 0; m < 3; ++m) {
        const float4* z4 = (const float4*)(feats[m] + ((size_t)i << 9) + d0);
        float4 za = z4[0], zb = z4[1];
        float v0 = dot8(za, zb, za, zb);
        const float4* c40 = (const float4*)(ws + OFF_CENT + (size_t)(m*3+0)*ND + d0);
        float v1 = dot8(za, zb, c40[0], c40[1]);
        const float4* c41 = (const float4*)(ws + OFF_CENT + (size_t)(m*3+1)*ND + d0);
        float v2 = dot8(za, zb, c41[0], c41[1]);
        const float4* c42 = (const float4*)(ws + OFF_CENT + (size_t)(m*3+2)*ND + d0);
        float v3 = dot8(za, zb, c42[0], c42[1]);
        v0 = wred(v0); v1 = wred(v1); v2 = wred(v2); v3 = wred(v3);
        if (lane == 0) {
            float* st = ws + OFF_ST + (size_t)(m*11)*NB + i;
            st[7*NB] = expf(v1 - 0.5f*(v0 + ws[OFF_C2 + m*3 + 0]));
            st[8*NB] = expf(v2 - 0.5f*(v0 + ws[OFF_C2 + m*3 + 1]));
            st[9*NB] = expf(v3 - 0.5f*(v0 + ws[OFF_C2 + m*3 + 2]));
        }
    }

    const float4* f4 = (const float4*)(fused + ((size_t)i << 9) + d0);
    float4 fa = f4[0], fb = f4[1];
    const float4* p0 = (const float4*)(ccp + 0*ND + d0);
    const float4* p1 = (const float4*)(ccp + 1*ND + d0);
    const float4* p2 = (const float4*)(ccp + 2*ND + d0);
    float l0 = wred(dot8(fa, fb, p0[0], p0[1]));
    float l1 = wred(dot8(fa, fb, p1[0], p1[1]));
    float l2 = wred(dot8(fa, fb, p2[0], p2[1]));
    int pf = 0; float lm = l0;
    if (l1 > lm) { pf = 1; lm = l1; }
    if (l2 > lm) { pf = 2; }
    const float4* av = (const float4*)(ws + OFF_AVG + (size_t)pf*ND + d0);
    float4 aa = av[0], ab = av[1];
    float dxx = fa.x-aa.x, dxy = fa.y-aa.y, dxz = fa.z-aa.z, dxw = fa.w-aa.w;
    float dyx = fb.x-ab.x, dyy = fb.y-ab.y, dyz = fb.z-ab.z, dyw = fb.w-ab.w;
    float dsq = wred(dxx*dxx + dxy*dxy + dxz*dxz + dxw*dxw +
                     dyx*dyx + dyy*dyy + dyz*dyz + dyw*dyw);
    if (lane == 0) {
        float wc = expf(-0.5f * dsq);
        #pragma unroll
        for (int c = 0; c < 3; ++c) {
            float v = (c == pf) ? wc : 0.0f;
            out[(size_t)i*NBC + NB + c]   = v;
            out[(size_t)(NB + c)*NBC + i] = v;
        }
    }
}

// ---- kE: B x B block. LDS-staged i-rows, broadcast ds_reads ----------------
// LDS row layout [64][36]: per m at offset m*12:
//   +0 a, +1 p0, +2 p1, +3 p2 | +4 l0, +5 l1, +6 l2, +7 pred | +8 F0, +9 F1, +10 F2, +11 pad
__global__ void __launch_bounds__(256) kE(const float* __restrict__ ws,
                                          float* __restrict__ out) {
    __shared__ float slds[64 * 36];
    int t = threadIdx.x;
    int j = blockIdx.x * 256 + t;
    int i0 = blockIdx.y * 64;
    const float* st = ws + OFF_ST;

    // stage 33 fields x 64 rows, coalesced in i
    #pragma unroll
    for (int idx = t; idx < 33 * 64; idx += 256) {
        int f = idx >> 6;          // global field 0..32
        int r = idx & 63;
        float v = st[(size_t)f * NB + i0 + r];
        int m = f / 11, k = f - m * 11;
        int lk = (k == 0) ? 0 : (k <= 3) ? k : (k <= 6) ? k : (k <= 9) ? k + 1 : 7;
        slds[r * 36 + m * 12 + lk] = v;
    }

    // per-thread j-side registers
    float ja[3], jp[3][3], jl[3][3], jF[3][3];
    int fiOff[3];
    #pragma unroll
    for (int m = 0; m < 3; ++m) {
        const float* base = st + (size_t)(m * 11) * NB + j;
        ja[m]    = base[0*NB];
        jp[m][0] = base[1*NB]; jp[m][1] = base[2*NB]; jp[m][2] = base[3*NB];
        jl[m][0] = base[4*NB]; jl[m][1] = base[5*NB]; jl[m][2] = base[6*NB];
        jF[m][0] = base[7*NB]; jF[m][1] = base[8*NB]; jF[m][2] = base[9*NB];
        fiOff[m] = m * 12 + 8 + (int)base[10*NB];   // F_i[pred_j], fixed per thread
    }
    __syncthreads();

    for (int r = 0; r < 64; ++r) {
        int i = i0 + r;
        const float* row = &slds[r * 36];
        float sum = 0.0f;
        #pragma unroll
        for (int m = 0; m < 3; ++m) {
            float4 A  = *(const float4*)(row + m * 12);      // a, p0, p1, p2
            float4 Lp = *(const float4*)(row + m * 12 + 4);  // l0, l1, l2, pred
            float Fi  = row[fiOff[m]];                       // F_i[pred_j]
            float tt = ja[m] + A.x
                     + A.y * jl[m][0] + A.z * jl[m][1] + A.w * jl[m][2]
                     + jp[m][0] * Lp.x + jp[m][1] * Lp.y + jp[m][2] * Lp.z;
            tt = fmaxf(tt, 0.0f);
            float pi = Lp.w;
            float Fj = (pi == 0.0f) ? jF[m][0] : ((pi == 1.0f) ? jF[m][1] : jF[m][2]);
            sum += tt * (Fi * Fj);
        }
        float v = (i == j) ? 0.0f : sum * (1.0f / 3.0f);
        __builtin_nontemporal_store(v, &out[(size_t)i * NBC + j]);
    }
}

extern "C" void kernel_launch(void* const* d_in, const int* in_sizes, int n_in,
                              void* d_out, int out_size, void* d_ws, size_t ws_size,
                              hipStream_t stream) {
    const float* tf    = (const float*)d_in[0];
    const float* af    = (const float*)d_in[1];
    const float* vf    = (const float*)d_in[2];
    const float* tl    = (const float*)d_in[3];
    const float* al    = (const float*)d_in[4];
    const float* vl    = (const float*)d_in[5];
    const float* fused = (const float*)d_in[6];
    const float* ccp   = (const float*)d_in[7];
    float* out = (float*)d_out;
    float* ws  = (float*)d_ws;

    hipMemcpyAsync(out + ADJ, fused, (size_t)NB * ND * sizeof(float),
                   hipMemcpyDeviceToDevice, stream);
    hipMemsetAsync(ws, 0, (OFF_CSUM + 9*ND) * sizeof(float), stream);

    kAB<<<NB/64, 256, 0, stream>>>(tf, af, vf, tl, al, vl, ws);
    kC<<<NC, 512, 0, stream>>>(ws, out);
    kD<<<NB/4, 256, 0, stream>>>(tf, af, vf, fused, ccp, ws, out);
    kE<<<dim3(NB/256, NB/64), 256, 0, stream>>>(ws, out);
}

// Round 4
// 173.577 us; speedup vs baseline: 1.1692x; 1.0659x over previous
//
#include <hip/hip_runtime.h>
#include <math.h>

#define NB 4096
#define NC 3
#define ND 512
#define NBC (NB + NC)                 // 4099
#define ADJ ((size_t)NBC * (size_t)NBC)

static constexpr float HID = 0.5f / 1.5f;       // 0.5 / DELTA
static constexpr float RS3 = 0.57735026919f;    // 1/sqrt(3)

// ---- ws layout (float offsets) ---------------------------------------------
#define OFF_CNT  0                         // int counts[9] (pad 16)
#define OFF_CSUM 16                        // atomic center sums [3][3][ND]
#define OFF_CENT (OFF_CSUM + 9*ND)         // finalized centers [3][3][ND]
#define OFF_C2   (OFF_CENT + 9*ND)         // ||center||^2 [9] (pad 16)
#define OFF_AVG  (OFF_C2 + 16)             // avg centers [3][ND]
#define OFF_ST   (OFF_AVG + 3*ND)          // SoA stats [30][NB]
// field f = m*10 + k:
//   k=0: A = 0.5 - HID*sum p log p + HID*log p2
//   k=1: p0   k=2: p1
//   k=3: s1 = (pred>=1)   k=4: s2 = (pred>=2)
//   k=5: d0 = HID*(lp0-lp2)   k=6: d1 = HID*(lp1-lp2)
//   k=7: F0/sqrt3   k=8: (F1-F0)/sqrt3   k=9: (F2-F1)/sqrt3   (kD fills 7..9)

__device__ __forceinline__ float dot8(const float4& a, const float4& b,
                                      const float4& c, const float4& d) {
    return a.x*c.x + a.y*c.y + a.z*c.z + a.w*c.w +
           b.x*d.x + b.y*d.y + b.z*d.z + b.w*d.w;
}

__device__ __forceinline__ float wred(float v) {
    #pragma unroll
    for (int off = 32; off > 0; off >>= 1) v += __shfl_xor(v, off, 64);
    return v;
}

// ---- kAB: label stats (SoA) + preds in LDS + class sums via atomics --------
__global__ void __launch_bounds__(256) kAB(const float* __restrict__ tf,
                                           const float* __restrict__ af,
                                           const float* __restrict__ vf,
                                           const float* __restrict__ tl,
                                           const float* __restrict__ al,
                                           const float* __restrict__ vl,
                                           float* __restrict__ ws) {
    __shared__ int spred[64][4];
    __shared__ int scnt[9];
    int t = threadIdx.x;
    if (t < 9) scnt[t] = 0;
    int r0 = blockIdx.x * 64;
    int r = t >> 2, m = t & 3;
    __syncthreads();
    if (m < 3) {
        const float* labs[3] = {tl, al, vl};
        int i = r0 + r;
        float p0 = labs[m][i*3+0], p1 = labs[m][i*3+1], p2 = labs[m][i*3+2];
        float l0 = logf(p0), l1 = logf(p1), l2 = logf(p2);
        float A  = 0.5f - HID * (p0*l0 + p1*l1 + p2*l2) + HID*l2;
        int pred = 0; float pm = p0;
        if (p1 > pm) { pred = 1; pm = p1; }
        if (p2 > pm) { pred = 2; }
        float* st = ws + OFF_ST + (size_t)(m*10)*NB + i;
        st[0*NB] = A;
        st[1*NB] = p0;  st[2*NB] = p1;
        st[3*NB] = (pred >= 1) ? 1.0f : 0.0f;
        st[4*NB] = (pred >= 2) ? 1.0f : 0.0f;
        st[5*NB] = HID*(l0 - l2);
        st[6*NB] = HID*(l1 - l2);
        spred[r][m] = pred;
        atomicAdd(&scnt[m*3 + pred], 1);
    }
    __syncthreads();
    if (t < 9) atomicAdd((int*)ws + OFF_CNT + t, scnt[t]);

    const float* feats[3] = {tf, af, vf};
    float acc[3][3][2] = {};
    for (int rr = 0; rr < 64; ++rr) {
        int i = r0 + rr;
        #pragma unroll
        for (int mm = 0; mm < 3; ++mm) {
            float z0 = feats[mm][(size_t)i*ND + t];
            float z1 = feats[mm][(size_t)i*ND + t + 256];
            int pr = spred[rr][mm];
            #pragma unroll
            for (int c = 0; c < 3; ++c) {
                acc[mm][c][0] += (pr == c) ? z0 : 0.0f;
                acc[mm][c][1] += (pr == c) ? z1 : 0.0f;
            }
        }
    }
    #pragma unroll
    for (int mm = 0; mm < 3; ++mm)
        #pragma unroll
        for (int c = 0; c < 3; ++c) {
            atomicAdd(&ws[OFF_CSUM + (mm*3+c)*ND + t],       acc[mm][c][0]);
            atomicAdd(&ws[OFF_CSUM + (mm*3+c)*ND + t + 256], acc[mm][c][1]);
        }
}

// ---- kC: finalize centers, ||c||^2, avg centers, node-feat tail, eye -------
__global__ void __launch_bounds__(512) kC(float* __restrict__ ws, float* __restrict__ out) {
    int c = blockIdx.x, d = threadIdx.x;
    const int* cnt = (const int*)ws + OFF_CNT;
    float sq[3], avg = 0.0f;
    #pragma unroll
    for (int m = 0; m < 3; ++m) {
        float inv = 1.0f / fmaxf((float)cnt[m*3+c], 1.0f);
        float v = ws[OFF_CSUM + (m*3+c)*ND + d] * inv;
        ws[OFF_CENT + (m*3+c)*ND + d] = v;
        sq[m] = v * v;
        avg += v;
    }
    avg *= (1.0f/3.0f);
    ws[OFF_AVG + c*ND + d] = avg;
    out[ADJ + (size_t)(NB + c)*ND + d] = avg;

    __shared__ float red[3][512];
    red[0][d] = sq[0]; red[1][d] = sq[1]; red[2][d] = sq[2];
    __syncthreads();
    for (int s = 256; s > 0; s >>= 1) {
        if (d < s) {
            red[0][d] += red[0][d+s];
            red[1][d] += red[1][d+s];
            red[2][d] += red[2][d+s];
        }
        __syncthreads();
    }
    if (d < 3) ws[OFF_C2 + d*3 + c] = red[d][0];
    if (c == 0 && d < 9) {
        int rr = d / 3, cc = d % 3;
        out[(size_t)(NB + rr)*NBC + NB + cc] = (rr == cc) ? 1.0f : 0.0f;
    }
}

// ---- kD: wave-per-sample F factors (scaled, differenced) + fused border ----
__global__ void __launch_bounds__(256) kD(const float* __restrict__ tf,
                                          const float* __restrict__ af,
                                          const float* __restrict__ vf,
                                          const float* __restrict__ fused,
                                          const float* __restrict__ ccp,
                                          float* __restrict__ ws,
                                          float* __restrict__ out) {
    int wid = threadIdx.x >> 6, lane = threadIdx.x & 63;
    int i = blockIdx.x * 4 + wid;
    const float* feats[3] = {tf, af, vf};
    int d0 = lane * 8;

    #pragma unroll
    for (int m = 0; m < 3; ++m) {
        const float4* z4 = (const float4*)(feats[m] + ((size_t)i << 9) + d0);
        float4 za = z4[0], zb = z4[1];
        float v0 = dot8(za, zb, za, zb);
        const float4* c40 = (const float4*)(ws + OFF_CENT + (size_t)(m*3+0)*ND + d0);
        float v1 = dot8(za, zb, c40[0], c40[1]);
        const float4* c41 = (const float4*)(ws + OFF_CENT + (size_t)(m*3+1)*ND + d0);
        float v2 = dot8(za, zb, c41[0], c41[1]);
        const float4* c42 = (const float4*)(ws + OFF_CENT + (size_t)(m*3+2)*ND + d0);
        float v3 = dot8(za, zb, c42[0], c42[1]);
        v0 = wred(v0); v1 = wred(v1); v2 = wred(v2); v3 = wred(v3);
        if (lane == 0) {
            float e0 = expf(v1 - 0.5f*(v0 + ws[OFF_C2 + m*3 + 0]));
            float e1 = expf(v2 - 0.5f*(v0 + ws[OFF_C2 + m*3 + 1]));
            float e2 = expf(v3 - 0.5f*(v0 + ws[OFF_C2 + m*3 + 2]));
            float* st = ws + OFF_ST + (size_t)(m*10)*NB + i;
            st[7*NB] = e0 * RS3;
            st[8*NB] = (e1 - e0) * RS3;
            st[9*NB] = (e2 - e1) * RS3;
        }
    }

    const float4* f4 = (const float4*)(fused + ((size_t)i << 9) + d0);
    float4 fa = f4[0], fb = f4[1];
    const float4* p0 = (const float4*)(ccp + 0*ND + d0);
    const float4* p1 = (const float4*)(ccp + 1*ND + d0);
    const float4* p2 = (const float4*)(ccp + 2*ND + d0);
    float l0 = wred(dot8(fa, fb, p0[0], p0[1]));
    float l1 = wred(dot8(fa, fb, p1[0], p1[1]));
    float l2 = wred(dot8(fa, fb, p2[0], p2[1]));
    int pf = 0; float lm = l0;
    if (l1 > lm) { pf = 1; lm = l1; }
    if (l2 > lm) { pf = 2; }
    const float4* av = (const float4*)(ws + OFF_AVG + (size_t)pf*ND + d0);
    float4 aa = av[0], ab = av[1];
    float dxx = fa.x-aa.x, dxy = fa.y-aa.y, dxz = fa.z-aa.z, dxw = fa.w-aa.w;
    float dyx = fb.x-ab.x, dyy = fb.y-ab.y, dyz = fb.z-ab.z, dyw = fb.w-ab.w;
    float dsq = wred(dxx*dxx + dxy*dxy + dxz*dxz + dxw*dxw +
                     dyx*dyx + dyy*dyy + dyz*dyz + dyw*dyw);
    if (lane == 0) {
        float wc = expf(-0.5f * dsq);
        #pragma unroll
        for (int c = 0; c < 3; ++c) {
            float v = (c == pf) ? wc : 0.0f;
            out[(size_t)i*NBC + NB + c]   = v;
            out[(size_t)(NB + c)*NBC + i] = v;
        }
    }
}

// ---- kE: B x B block. 1024j x 32i tile, 4 j per thread, select-free --------
// LDS row layout [32][36]: per m at m*12:
//   +0 A, +1 p0, +2 p1, +3 s1 | +4 s2, +5 d0, +6 d1, +7 F0 | +8 DF1, +9 DF2
__global__ void __launch_bounds__(256) kE(const float* __restrict__ ws,
                                          float* __restrict__ out) {
    __shared__ __align__(16) float slds[32 * 36];
    int t = threadIdx.x;
    int jbase = blockIdx.x * 1024;
    int i0 = blockIdx.y * 32;
    const float* st = ws + OFF_ST;

    // stage 30 fields x 32 rows (coalesced in i)
    for (int idx = t; idx < 960; idx += 256) {
        int f = idx >> 5, r = idx & 31;
        int m = f / 10, k = f - m * 10;
        slds[r * 36 + m * 12 + k] = st[(size_t)f * NB + i0 + r];
    }

    // j-side registers: J[m][k][q], j = jbase + q*256 + t
    float J[3][10][4];
    #pragma unroll
    for (int m = 0; m < 3; ++m)
        #pragma unroll
        for (int k = 0; k < 10; ++k) {
            const float* b = st + (size_t)(m * 10 + k) * NB + jbase + t;
            #pragma unroll
            for (int q = 0; q < 4; ++q) J[m][k][q] = b[q * 256];
        }
    __syncthreads();

    float* p = out + (size_t)i0 * NBC + jbase + t;
    for (int r = 0; r < 32; ++r) {
        int i = i0 + r;
        float acc0 = 0.0f, acc1 = 0.0f, acc2 = 0.0f, acc3 = 0.0f;
        #pragma unroll
        for (int m = 0; m < 3; ++m) {
            float4 Q1 = *(const float4*)(slds + r * 36 + m * 12);      // A,p0,p1,s1
            float4 Q2 = *(const float4*)(slds + r * 36 + m * 12 + 4);  // s2,d0,d1,F0
            float2 Q3 = *(const float2*)(slds + r * 36 + m * 12 + 8);  // DF1,DF2
            float accq[4];
            #pragma unroll
            for (int q = 0; q < 4; ++q) {
                float tt = Q1.x + J[m][0][q];                // A_i + A_j
                tt = fmaf(Q1.y, J[m][5][q], tt);             // p0_i * d0_j
                tt = fmaf(Q1.z, J[m][6][q], tt);             // p1_i * d1_j
                tt = fmaf(J[m][1][q], Q2.y, tt);             // p0_j * d0_i
                tt = fmaf(J[m][2][q], Q2.z, tt);             // p1_j * d1_i
                tt = fmaxf(tt, 0.0f);
                // Fi = F0_i + s1_j*DF1_i + s2_j*DF2_i
                float Fi = fmaf(J[m][4][q], Q3.y, fmaf(J[m][3][q], Q3.x, Q2.w));
                // Fj = F0_j + s1_i*DF1_j + s2_i*DF2_j
                float Fj = fmaf(Q2.x, J[m][9][q], fmaf(Q1.w, J[m][8][q], J[m][7][q]));
                accq[q] = tt * (Fi * Fj);
            }
            acc0 += accq[0]; acc1 += accq[1]; acc2 += accq[2]; acc3 += accq[3];
        }
        int jt = jbase + t;
        float v0 = (i == jt)        ? 0.0f : acc0;
        float v1 = (i == jt + 256)  ? 0.0f : acc1;
        float v2 = (i == jt + 512)  ? 0.0f : acc2;
        float v3 = (i == jt + 768)  ? 0.0f : acc3;
        __builtin_nontemporal_store(v0, p);
        __builtin_nontemporal_store(v1, p + 256);
        __builtin_nontemporal_store(v2, p + 512);
        __builtin_nontemporal_store(v3, p + 768);
        p += NBC;
    }
}

extern "C" void kernel_launch(void* const* d_in, const int* in_sizes, int n_in,
                              void* d_out, int out_size, void* d_ws, size_t ws_size,
                              hipStream_t stream) {
    const float* tf    = (const float*)d_in[0];
    const float* af    = (const float*)d_in[1];
    const float* vf    = (const float*)d_in[2];
    const float* tl    = (const float*)d_in[3];
    const float* al    = (const float*)d_in[4];
    const float* vl    = (const float*)d_in[5];
    const float* fused = (const float*)d_in[6];
    const float* ccp   = (const float*)d_in[7];
    float* out = (float*)d_out;
    float* ws  = (float*)d_ws;

    hipMemcpyAsync(out + ADJ, fused, (size_t)NB * ND * sizeof(float),
                   hipMemcpyDeviceToDevice, stream);
    hipMemsetAsync(ws, 0, (OFF_CSUM + 9*ND) * sizeof(float), stream);

    kAB<<<NB/64, 256, 0, stream>>>(tf, af, vf, tl, al, vl, ws);
    kC<<<NC, 512, 0, stream>>>(ws, out);
    kD<<<NB/4, 256, 0, stream>>>(tf, af, vf, fused, ccp, ws, out);
    kE<<<dim3(NB/1024, NB/32), 256, 0, stream>>>(ws, out);
}

// Round 5
// 155.794 us; speedup vs baseline: 1.3026x; 1.1141x over previous
//
#include <hip/hip_runtime.h>
#include <math.h>

#define NB 4096
#define NC 3
#define ND 512
#define NBC (NB + NC)                 // 4099
#define ADJ ((size_t)NBC * (size_t)NBC)

static constexpr float HID = 0.5f / 1.5f;       // 0.5 / DELTA
static constexpr float RS3 = 0.57735026919f;    // 1/sqrt(3)

// ---- ws layout (float offsets) ---------------------------------------------
#define OFF_CNT  0                         // int counts[9] (pad 16)
#define OFF_CSUM 16                        // atomic center sums [3][3][ND]
#define OFF_ST   (OFF_CSUM + 9*ND)         // SoA stats [30][NB]  (j-side, coalesced)
#define OFF_AOS  (OFF_ST + 30*NB)          // AoS stats [NB][36]  (i-side, scalar)
// field k per modality m:
//   k=0: A = 0.5 - HID*sum p log p + HID*log p2
//   k=1: p0   k=2: p1
//   k=3: s1 = (pred>=1)   k=4: s2 = (pred>=2)
//   k=5: d0 = HID*(lp0-lp2)   k=6: d1 = HID*(lp1-lp2)
//   k=7: F0/sqrt3   k=8: (F1-F0)/sqrt3   k=9: (F2-F1)/sqrt3   (kD fills 7..9)
// SoA: addr = OFF_ST + (m*10+k)*NB + i
// AoS: addr = OFF_AOS + i*36 + m*12 + k   (k=7..9 stored at slots 7,8,9)

__device__ __forceinline__ float dot8(const float4& a, const float4& b,
                                      const float4& c, const float4& d) {
    return a.x*c.x + a.y*c.y + a.z*c.z + a.w*c.w +
           b.x*d.x + b.y*d.y + b.z*d.z + b.w*d.w;
}

__device__ __forceinline__ float wred(float v) {
    #pragma unroll
    for (int off = 32; off > 0; off >>= 1) v += __shfl_xor(v, off, 64);
    return v;
}

// ---- kAB: label stats (SoA+AoS) + per-block class sums via atomics ---------
__global__ void __launch_bounds__(256) kAB(const float* __restrict__ tf,
                                           const float* __restrict__ af,
                                           const float* __restrict__ vf,
                                           const float* __restrict__ tl,
                                           const float* __restrict__ al,
                                           const float* __restrict__ vl,
                                           float* __restrict__ ws) {
    __shared__ int spred[16][3];
    __shared__ int scnt[9];
    int t = threadIdx.x;
    if (t < 9) scnt[t] = 0;
    int r0 = blockIdx.x * 16;
    __syncthreads();
    if (t < 48) {
        int r = t / 3, m = t % 3;
        const float* labs[3] = {tl, al, vl};
        int i = r0 + r;
        float p0 = labs[m][i*3+0], p1 = labs[m][i*3+1], p2 = labs[m][i*3+2];
        float l0 = logf(p0), l1 = logf(p1), l2 = logf(p2);
        float A  = 0.5f - HID * (p0*l0 + p1*l1 + p2*l2) + HID*l2;
        int pred = 0; float pm = p0;
        if (p1 > pm) { pred = 1; pm = p1; }
        if (p2 > pm) { pred = 2; }
        float s1 = (pred >= 1) ? 1.0f : 0.0f;
        float s2 = (pred >= 2) ? 1.0f : 0.0f;
        float d0 = HID*(l0 - l2), d1 = HID*(l1 - l2);
        float* st = ws + OFF_ST + (size_t)(m*10)*NB + i;
        st[0*NB] = A;  st[1*NB] = p0; st[2*NB] = p1;
        st[3*NB] = s1; st[4*NB] = s2; st[5*NB] = d0; st[6*NB] = d1;
        float* ao = ws + OFF_AOS + (size_t)i*36 + m*12;
        ao[0] = A;  ao[1] = p0; ao[2] = p1; ao[3] = s1;
        ao[4] = s2; ao[5] = d0; ao[6] = d1;
        spred[r][m] = pred;
        atomicAdd(&scnt[m*3 + pred], 1);
    }
    __syncthreads();
    if (t < 9) atomicAdd((int*)ws + OFF_CNT + t, scnt[t]);

    const float* feats[3] = {tf, af, vf};
    float acc[3][3][2] = {};
    #pragma unroll
    for (int rr = 0; rr < 16; ++rr) {
        int i = r0 + rr;
        #pragma unroll
        for (int mm = 0; mm < 3; ++mm) {
            float z0 = feats[mm][(size_t)i*ND + t];
            float z1 = feats[mm][(size_t)i*ND + t + 256];
            int pr = spred[rr][mm];
            #pragma unroll
            for (int c = 0; c < 3; ++c) {
                acc[mm][c][0] += (pr == c) ? z0 : 0.0f;
                acc[mm][c][1] += (pr == c) ? z1 : 0.0f;
            }
        }
    }
    #pragma unroll
    for (int mm = 0; mm < 3; ++mm)
        #pragma unroll
        for (int c = 0; c < 3; ++c) {
            atomicAdd(&ws[OFF_CSUM + (mm*3+c)*ND + t],       acc[mm][c][0]);
            atomicAdd(&ws[OFF_CSUM + (mm*3+c)*ND + t + 256], acc[mm][c][1]);
        }
}

// ---- kD: F factors + fused border + (folded kC: norms inline, tail, eye) ---
__global__ void __launch_bounds__(256) kD(const float* __restrict__ tf,
                                          const float* __restrict__ af,
                                          const float* __restrict__ vf,
                                          const float* __restrict__ fused,
                                          const float* __restrict__ ccp,
                                          float* __restrict__ ws,
                                          float* __restrict__ out) {
    int wid = threadIdx.x >> 6, lane = threadIdx.x & 63;
    int i = blockIdx.x * 4 + wid;
    const float* feats[3] = {tf, af, vf};
    int d0 = lane * 8;

    const int* cnt = (const int*)ws + OFF_CNT;
    float inv[3][3];
    #pragma unroll
    for (int m = 0; m < 3; ++m)
        #pragma unroll
        for (int c = 0; c < 3; ++c)
            inv[m][c] = 1.0f / fmaxf((float)cnt[m*3+c], 1.0f);

    #pragma unroll
    for (int m = 0; m < 3; ++m) {
        const float4* z4 = (const float4*)(feats[m] + ((size_t)i << 9) + d0);
        float4 za = z4[0], zb = z4[1];
        float v0 = dot8(za, zb, za, zb);
        float vc[3], nc[3];
        #pragma unroll
        for (int c = 0; c < 3; ++c) {
            const float4* s4 = (const float4*)(ws + OFF_CSUM + (size_t)(m*3+c)*ND + d0);
            float4 ca = s4[0], cb = s4[1];
            float iv = inv[m][c];
            ca.x *= iv; ca.y *= iv; ca.z *= iv; ca.w *= iv;
            cb.x *= iv; cb.y *= iv; cb.z *= iv; cb.w *= iv;
            vc[c] = dot8(za, zb, ca, cb);
            nc[c] = dot8(ca, cb, ca, cb);
        }
        v0 = wred(v0);
        vc[0] = wred(vc[0]); vc[1] = wred(vc[1]); vc[2] = wred(vc[2]);
        nc[0] = wred(nc[0]); nc[1] = wred(nc[1]); nc[2] = wred(nc[2]);
        if (lane == 0) {
            float e0 = expf(vc[0] - 0.5f*(v0 + nc[0]));
            float e1 = expf(vc[1] - 0.5f*(v0 + nc[1]));
            float e2 = expf(vc[2] - 0.5f*(v0 + nc[2]));
            float F0 = e0 * RS3, DF1 = (e1 - e0) * RS3, DF2 = (e2 - e1) * RS3;
            float* st = ws + OFF_ST + (size_t)(m*10)*NB + i;
            st[7*NB] = F0; st[8*NB] = DF1; st[9*NB] = DF2;
            float* ao = ws + OFF_AOS + (size_t)i*36 + m*12;
            ao[7] = F0; ao[8] = DF1; ao[9] = DF2;
        }
    }

    // fused pseudo-label argmax + w_center
    const float4* f4 = (const float4*)(fused + ((size_t)i << 9) + d0);
    float4 fa = f4[0], fb = f4[1];
    const float4* p0 = (const float4*)(ccp + 0*ND + d0);
    const float4* p1 = (const float4*)(ccp + 1*ND + d0);
    const float4* p2 = (const float4*)(ccp + 2*ND + d0);
    float l0 = wred(dot8(fa, fb, p0[0], p0[1]));
    float l1 = wred(dot8(fa, fb, p1[0], p1[1]));
    float l2 = wred(dot8(fa, fb, p2[0], p2[1]));
    int pf = 0; float lm = l0;
    if (l1 > lm) { pf = 1; lm = l1; }
    if (l2 > lm) { pf = 2; }
    // avg-center slice for class pf, rebuilt from CSUM
    float4 aa = {0,0,0,0}, ab = {0,0,0,0};
    #pragma unroll
    for (int m = 0; m < 3; ++m) {
        const float4* s4 = (const float4*)(ws + OFF_CSUM + (size_t)(m*3+pf)*ND + d0);
        float4 ca = s4[0], cb = s4[1];
        float iv = inv[m][pf] * (1.0f/3.0f);
        aa.x = fmaf(ca.x, iv, aa.x); aa.y = fmaf(ca.y, iv, aa.y);
        aa.z = fmaf(ca.z, iv, aa.z); aa.w = fmaf(ca.w, iv, aa.w);
        ab.x = fmaf(cb.x, iv, ab.x); ab.y = fmaf(cb.y, iv, ab.y);
        ab.z = fmaf(cb.z, iv, ab.z); ab.w = fmaf(cb.w, iv, ab.w);
    }
    float dxx = fa.x-aa.x, dxy = fa.y-aa.y, dxz = fa.z-aa.z, dxw = fa.w-aa.w;
    float dyx = fb.x-ab.x, dyy = fb.y-ab.y, dyz = fb.z-ab.z, dyw = fb.w-ab.w;
    float dsq = wred(dxx*dxx + dxy*dxy + dxz*dxz + dxw*dxw +
                     dyx*dyx + dyy*dyy + dyz*dyz + dyw*dyw);
    if (lane == 0) {
        float wc = expf(-0.5f * dsq);
        #pragma unroll
        for (int c = 0; c < 3; ++c) {
            float v = (c == pf) ? wc : 0.0f;
            out[(size_t)i*NBC + NB + c]   = v;
            out[(size_t)(NB + c)*NBC + i] = v;
        }
    }

    // folded kC epilogue: node-feature tail rows (blocks 0..2) + eye (block 0)
    if (blockIdx.x < 3) {
        int c = blockIdx.x;
        for (int d = threadIdx.x; d < ND; d += 256) {
            float av = 0.0f;
            #pragma unroll
            for (int m = 0; m < 3; ++m)
                av = fmaf(ws[OFF_CSUM + (size_t)(m*3+c)*ND + d],
                          inv[m][c] * (1.0f/3.0f), av);
            out[ADJ + (size_t)(NB + c)*ND + d] = av;
        }
        if (c == 0 && threadIdx.x < 9) {
            int rr = threadIdx.x / 3, cc = threadIdx.x % 3;
            out[(size_t)(NB + rr)*NBC + NB + cc] = (rr == cc) ? 1.0f : 0.0f;
        }
    }
}

// ---- kE: B x B block. Scalar i-side (AoS via sK$), no LDS, 4 j/thread ------
__global__ void __launch_bounds__(256) kE(const float* __restrict__ ws,
                                          float* __restrict__ out) {
    int t = threadIdx.x;
    int jbase = blockIdx.x * 1024;
    int i0 = blockIdx.y * 32;
    const float* st  = ws + OFF_ST;
    const float* aos = ws + OFF_AOS;

    // j-side registers: J[m][k][q], j = jbase + q*256 + t  (coalesced SoA)
    float J[3][10][4];
    #pragma unroll
    for (int m = 0; m < 3; ++m)
        #pragma unroll
        for (int k = 0; k < 10; ++k) {
            const float* b = st + (size_t)(m * 10 + k) * NB + jbase + t;
            #pragma unroll
            for (int q = 0; q < 4; ++q) J[m][k][q] = b[q * 256];
        }

    float* p = out + (size_t)i0 * NBC + jbase + t;
    int jt = jbase + t;
    for (int r = 0; r < 32; ++r) {
        int i = __builtin_amdgcn_readfirstlane(i0 + r);   // force scalar path
        const float* row = aos + (size_t)i * 36;
        float acc0 = 0.0f, acc1 = 0.0f, acc2 = 0.0f, acc3 = 0.0f;
        #pragma unroll
        for (int m = 0; m < 3; ++m) {
            float4 Q1 = *(const float4*)(row + m * 12);      // A,p0,p1,s1
            float4 Q2 = *(const float4*)(row + m * 12 + 4);  // s2,d0,d1,F0
            float2 Q3 = *(const float2*)(row + m * 12 + 8);  // DF1,DF2
            float accq[4];
            #pragma unroll
            for (int q = 0; q < 4; ++q) {
                float tt = Q1.x + J[m][0][q];                // A_i + A_j
                tt = fmaf(Q1.y, J[m][5][q], tt);             // p0_i * d0_j
                tt = fmaf(Q1.z, J[m][6][q], tt);             // p1_i * d1_j
                tt = fmaf(J[m][1][q], Q2.y, tt);             // p0_j * d0_i
                tt = fmaf(J[m][2][q], Q2.z, tt);             // p1_j * d1_i
                tt = fmaxf(tt, 0.0f);
                float Fi = fmaf(J[m][4][q], Q3.y, fmaf(J[m][3][q], Q3.x, Q2.w));
                float Fj = fmaf(Q2.x, J[m][9][q], fmaf(Q1.w, J[m][8][q], J[m][7][q]));
                accq[q] = tt * (Fi * Fj);
            }
            acc0 += accq[0]; acc1 += accq[1]; acc2 += accq[2]; acc3 += accq[3];
        }
        int ii = i0 + r;
        float v0 = (ii == jt)        ? 0.0f : acc0;
        float v1 = (ii == jt + 256)  ? 0.0f : acc1;
        float v2 = (ii == jt + 512)  ? 0.0f : acc2;
        float v3 = (ii == jt + 768)  ? 0.0f : acc3;
        __builtin_nontemporal_store(v0, p);
        __builtin_nontemporal_store(v1, p + 256);
        __builtin_nontemporal_store(v2, p + 512);
        __builtin_nontemporal_store(v3, p + 768);
        p += NBC;
    }
}

extern "C" void kernel_launch(void* const* d_in, const int* in_sizes, int n_in,
                              void* d_out, int out_size, void* d_ws, size_t ws_size,
                              hipStream_t stream) {
    const float* tf    = (const float*)d_in[0];
    const float* af    = (const float*)d_in[1];
    const float* vf    = (const float*)d_in[2];
    const float* tl    = (const float*)d_in[3];
    const float* al    = (const float*)d_in[4];
    const float* vl    = (const float*)d_in[5];
    const float* fused = (const float*)d_in[6];
    const float* ccp   = (const float*)d_in[7];
    float* out = (float*)d_out;
    float* ws  = (float*)d_ws;

    hipMemcpyAsync(out + ADJ, fused, (size_t)NB * ND * sizeof(float),
                   hipMemcpyDeviceToDevice, stream);
    hipMemsetAsync(ws, 0, (OFF_CSUM + 9*ND) * sizeof(float), stream);

    kAB<<<NB/16, 256, 0, stream>>>(tf, af, vf, tl, al, vl, ws);
    kD<<<NB/4, 256, 0, stream>>>(tf, af, vf, fused, ccp, ws, out);
    kE<<<dim3(NB/1024, NB/32), 256, 0, stream>>>(ws, out);
}